// Round 4
// baseline (222.711 us; speedup 1.0000x reference)
//
#include <hip/hip_runtime.h>
#include <hip/hip_bf16.h>
#include <hip/hip_cooperative_groups.h>
#include <math.h>

namespace cg = cooperative_groups;

#define NN     8192
#define FDIM   64
#define EDGES  262144
#define BATCH  2
#define ALPHA  0.2f

#define NB     128        // coarse buckets (src >> 6)
#define SRCB   64         // srcs per bucket
#define BCAP   2432       // mean 2048 + ~8.5 sigma
#define NBLK   256
#define NTHR   1024

// ---- ws layout ----
#define OFF_WH   0u           // float[B*N*64]  4 MB
#define OFF_S1   4194304u     // float[B*N]     64 KB
#define OFF_S2   4259840u     // float[B*N]     64 KB
#define OFF_CNT  4325376u     // int[128]
#define OFF_CRS  4325888u     // uint2[128*2432] ~2.5 MB

// LDS overlay (phases separated by barriers):
//   A-prep:   float sW[64*65] (16640 B) | float sH[16*4*64] (16384 B)
//   A-bucket: int bhist[128] | int bbase[128]
//   B-row:    uint2 grp[BCAP] (19456 B) | int rhist[64] | int roffs[64]
#define SMEM_BYTES 33024

__global__ __launch_bounds__(NTHR, 4) void gat_kernel(
    const float* __restrict__ h, const float* __restrict__ W,
    const float* __restrict__ a, const int* __restrict__ ei,
    const float* __restrict__ ew,
    float* __restrict__ Wh, float* __restrict__ s1, float* __restrict__ s2,
    int* __restrict__ cnt, uint2* __restrict__ coarse,
    float* __restrict__ out) {
  __shared__ __align__(16) char smem[SMEM_BYTES];
  int tid = threadIdx.x, lane = tid & 63, w = tid >> 6;
  int blk = blockIdx.x;

  // ================= Phase A1: Wh = h@W^T, s1, s2 =================
  {
    float* sW = (float*)smem;                  // [64][65]
    float* sH = (float*)(smem + 16640);        // [16][4][64]
    for (int i = tid; i < 4096; i += NTHR) sW[(i >> 6) * 65 + (i & 63)] = W[i];
    int nn0 = blk * 64 + w * 4;                // this wave's 4 rows in [0, B*N)
#pragma unroll
    for (int r = 0; r < 4; ++r)
      sH[(w * 4 + r) * 64 + lane] = h[(size_t)(nn0 + r) * 64 + lane];
    __syncthreads();

    const float* wp = sW + lane * 65;          // bank (lane+k)%32: 2-way, free
    const float* hp = sH + (w * 4) * 64;
    float acc[4] = {0.f, 0.f, 0.f, 0.f};
#pragma unroll 8
    for (int k = 0; k < 64; ++k) {
      float wv = wp[k];
      acc[0] += hp[k] * wv;
      acc[1] += hp[64 + k] * wv;
      acc[2] += hp[128 + k] * wv;
      acc[3] += hp[192 + k] * wv;
    }
    float a1 = a[lane], a2 = a[64 + lane];
#pragma unroll
    for (int r = 0; r < 4; ++r) {
      int nn = nn0 + r;
      Wh[(size_t)nn * 64 + lane] = acc[r];
      float p1 = acc[r] * a1, p2 = acc[r] * a2;
#pragma unroll
      for (int off = 32; off; off >>= 1) {
        p1 += __shfl_xor(p1, off, 64);
        p2 += __shfl_xor(p2, off, 64);
      }
      if (lane == 0) { s1[nn] = p1; s2[nn] = p2; }
    }
  }

  // ================= Phase A2: bucket edges by src>>6 =================
  {
    __syncthreads();                           // before LDS reuse
    int* bhist = (int*)smem;
    int* bbase = (int*)(smem + 512);
    int e = blk * 1024 + tid;
    int s = ei[e], d = ei[EDGES + e];
    int g = s >> 6;
    if (tid < NB) bhist[tid] = 0;
    __syncthreads();
    int rank = atomicAdd(&bhist[g], 1);
    __syncthreads();
    if (tid < NB) bbase[tid] = atomicAdd(&cnt[tid], bhist[tid]);
    __syncthreads();
    int pos = bbase[g] + rank;
    if (pos < BCAP)
      coarse[g * BCAP + pos] = make_uint2(((unsigned)e << 13) | (unsigned)d, (unsigned)s);
  }

  __threadfence();
  cg::this_grid().sync();

  // ================= Phase B: per-src dedupe+softmax+gather =================
  uint2* grp   = (uint2*)smem;                 // [BCAP]
  int*   rhist = (int*)(smem + 19456);         // [64]
  int*   roffs = (int*)(smem + 19712);         // [64]
  int xcd = blk & 7;
  int b = xcd >> 2;                            // XCD 0-3 -> batch 0, 4-7 -> batch 1
  int g = (blk >> 3) * 4 + (xcd & 3);
  int T = cnt[g]; if (T > BCAP) T = BCAP;
  const float* s1b = s1 + b * NN;
  const float* s2b = s2 + b * NN;
  if (tid < SRCB) rhist[tid] = 0;
  __syncthreads();

  unsigned mpk[3]; float mv[3]; int msl[3], mrk[3]; bool mok[3];
#pragma unroll
  for (int j = 0; j < 3; ++j) {
    int i = tid + j * 1024;
    mok[j] = (i < T);
    mpk[j] = 0; mv[j] = 0.f; msl[j] = 0; mrk[j] = 0;
    if (mok[j]) {
      uint2 E = coarse[g * BCAP + i];
      int dst = (int)(E.x & 0x1FFFu);
      int eid = (int)(E.x >> 13);
      int src = (int)E.y;
      float x = s1b[src] + s2b[dst];
      float val = (x > 0.f ? x : ALPHA * x) * ew[eid];
      mpk[j] = E.x; mv[j] = val; msl[j] = src & 63;
      mrk[j] = atomicAdd(&rhist[msl[j]], 1);
    }
  }
  __syncthreads();
  if (tid < 64) {                              // exclusive scan of 64 counts
    int c = rhist[tid];
    int x = c;
#pragma unroll
    for (int off = 1; off < 64; off <<= 1) {
      int y = __shfl_up(x, off, 64);
      if (tid >= off) x += y;
    }
    roffs[tid] = x - c;
  }
  __syncthreads();
#pragma unroll
  for (int j = 0; j < 3; ++j)
    if (mok[j]) grp[roffs[msl[j]] + mrk[j]] = make_uint2(mpk[j], __float_as_uint(mv[j]));
  __syncthreads();

  const float* Whb = Wh + (size_t)b * NN * FDIM;
  for (int q = 0; q < 4; ++q) {
    int slo = w * 4 + q;
    int beg = roffs[slo];
    int deg = rhist[slo];
    float acc = 0.f;
    if (deg > 0) {
      float inv;
      if (deg <= 64) {
        unsigned k0 = 0; float v0 = 0.f;
        if (lane < deg) { uint2 E = grp[beg + lane]; k0 = E.x; v0 = __uint_as_float(E.y); }
        for (int j = 0; j < deg; ++j) {
          unsigned q2 = __shfl(k0, j, 64);
          if ((((q2 ^ k0) & 0x1FFFu) == 0u) & (q2 > k0)) v0 = 0.f;   // dup loser
        }
        float m = (v0 != 0.f) ? v0 : -INFINITY;
#pragma unroll
        for (int off = 32; off; off >>= 1) m = fmaxf(m, __shfl_xor(m, off, 64));
        float p = (v0 != 0.f) ? expf(v0 - m) : 0.f;
        float sum = p;
#pragma unroll
        for (int off = 32; off; off >>= 1) sum += __shfl_xor(sum, off, 64);
        inv = (sum > 0.f) ? 1.f / sum : 0.f;
        if (lane < deg) grp[beg + lane].y = __float_as_uint(p);
      } else {                                  // deg in (64,128] — ~1e-7 of rows
        int dg = deg > 128 ? 128 : deg;
        deg = dg;
        unsigned k0 = 0, k1 = 0; float v0 = 0.f, v1 = 0.f;
        { uint2 E = grp[beg + lane]; k0 = E.x; v0 = __uint_as_float(E.y); }
        if (lane + 64 < dg) { uint2 E = grp[beg + lane + 64]; k1 = E.x; v1 = __uint_as_float(E.y); }
        for (int j = 0; j < 64; ++j) {
          unsigned q2 = __shfl(k0, j, 64);
          if ((((q2 ^ k0) & 0x1FFFu) == 0u) & (q2 > k0)) v0 = 0.f;
          if ((((q2 ^ k1) & 0x1FFFu) == 0u) & (q2 > k1)) v1 = 0.f;
        }
        for (int j = 0; j < dg - 64; ++j) {
          unsigned q2 = __shfl(k1, j, 64);
          if ((((q2 ^ k0) & 0x1FFFu) == 0u) & (q2 > k0)) v0 = 0.f;
          if ((((q2 ^ k1) & 0x1FFFu) == 0u) & (q2 > k1)) v1 = 0.f;
        }
        float m0 = (v0 != 0.f) ? v0 : -INFINITY;
        float m1 = (v1 != 0.f) ? v1 : -INFINITY;
        float m = fmaxf(m0, m1);
#pragma unroll
        for (int off = 32; off; off >>= 1) m = fmaxf(m, __shfl_xor(m, off, 64));
        float p0 = (v0 != 0.f) ? expf(v0 - m) : 0.f;
        float p1 = (v1 != 0.f) ? expf(v1 - m) : 0.f;
        float sum = p0 + p1;
#pragma unroll
        for (int off = 32; off; off >>= 1) sum += __shfl_xor(sum, off, 64);
        inv = (sum > 0.f) ? 1.f / sum : 0.f;
        grp[beg + lane].y = __float_as_uint(p0);
        if (lane + 64 < dg) grp[beg + lane + 64].y = __float_as_uint(p1);
      }
      // gather: wave-uniform LDS broadcast {pk,p}, unconditional FMA, 8 in flight
      int k = 0;
      for (; k + 8 <= deg; k += 8) {
#pragma unroll
        for (int u = 0; u < 8; ++u) {
          uint2 E = grp[beg + k + u];
          acc += __uint_as_float(E.y) * Whb[(E.x & 0x1FFFu) * 64 + lane];
        }
      }
      for (; k < deg; ++k) {
        uint2 E = grp[beg + k];
        acc += __uint_as_float(E.y) * Whb[(E.x & 0x1FFFu) * 64 + lane];
      }
      acc *= inv;
    }
    int n = g * SRCB + slo;
    out[((size_t)b * NN + n) * 64 + lane] = acc > 0.f ? acc : expm1f(acc);
  }
}

extern "C" void kernel_launch(void* const* d_in, const int* in_sizes, int n_in,
                              void* d_out, int out_size, void* d_ws, size_t ws_size,
                              hipStream_t stream) {
  const float* h  = (const float*)d_in[0];
  const float* W  = (const float*)d_in[1];
  const float* a  = (const float*)d_in[2];
  const int*   ei = (const int*)d_in[3];
  const float* ew = (const float*)d_in[4];
  float* out = (float*)d_out;

  char* ws = (char*)d_ws;
  float* Wh     = (float*)(ws + OFF_WH);
  float* s1     = (float*)(ws + OFF_S1);
  float* s2     = (float*)(ws + OFF_S2);
  int*   cnt    = (int*)(ws + OFF_CNT);
  uint2* coarse = (uint2*)(ws + OFF_CRS);

  hipMemsetAsync(cnt, 0, NB * sizeof(int), stream);

  void* args[] = {(void*)&h, (void*)&W, (void*)&a, (void*)&ei, (void*)&ew,
                  (void*)&Wh, (void*)&s1, (void*)&s2, (void*)&cnt,
                  (void*)&coarse, (void*)&out};
  hipLaunchCooperativeKernel((const void*)gat_kernel, dim3(NBLK), dim3(NTHR),
                             args, 0, stream);
}

// Round 5
// 110.416 us; speedup vs baseline: 2.0170x; 2.0170x over previous
//
#include <hip/hip_runtime.h>
#include <hip/hip_bf16.h>
#include <math.h>

#define NN     8192
#define FDIM   64
#define EDGES  262144
#define BATCH  2
#define ALPHA  0.2f

#define NB     256        // coarse buckets (src >> 5)
#define SRCB   32         // srcs per bucket
#define BCAP   1280       // mean 1024 + 8 sigma
#define ROWCAP 128        // per-src cap (P(deg>128), Poisson(32): negligible)

// ---- ws layout ----
#define OFF_WH   0u           // float[B*N*64]  4 MB
#define OFF_S1   4194304u     // float[B*N]     64 KB
#define OFF_S2   4259840u     // float[B*N]     64 KB
#define OFF_CNT  4325376u     // int[256]       1 KB
#define OFF_CRS  4326400u     // uint2[256*1280] 2.5 MB   (total ~6.6 MB)

// K1: 256 blocks x 1024. Per block: prep 64 rows (Wh,s1,s2) + bucket 1024 edges.
__global__ __launch_bounds__(1024) void stage1_kernel(
    const float* __restrict__ h, const float* __restrict__ W,
    const float* __restrict__ a, const int* __restrict__ ei,
    float* __restrict__ Wh, float* __restrict__ s1, float* __restrict__ s2,
    int* __restrict__ cnt, uint2* __restrict__ coarse) {
  __shared__ __align__(16) char smem[33024];   // sW 16640 | sH 16384; reused as hist
  int tid = threadIdx.x, lane = tid & 63, w = tid >> 6;
  int blk = blockIdx.x;

  // ---- A1: Wh = h@W^T, s1, s2 (64 rows per block) ----
  {
    float* sW = (float*)smem;                  // [64][65] pad: (lane+k)%32, 2-way free
    float* sH = (float*)(smem + 16640);        // [64][64]
    for (int i = tid; i < 4096; i += 1024) sW[(i >> 6) * 65 + (i & 63)] = W[i];
    int nn0 = blk * 64 + w * 4;                // [0, B*N)
#pragma unroll
    for (int r = 0; r < 4; ++r)
      sH[(w * 4 + r) * 64 + lane] = h[(size_t)(nn0 + r) * 64 + lane];
    __syncthreads();

    const float* wp = sW + lane * 65;
    const float* hp = sH + (w * 4) * 64;
    float acc[4] = {0.f, 0.f, 0.f, 0.f};
#pragma unroll 8
    for (int k = 0; k < 64; ++k) {
      float wv = wp[k];
      acc[0] += hp[k] * wv;
      acc[1] += hp[64 + k] * wv;
      acc[2] += hp[128 + k] * wv;
      acc[3] += hp[192 + k] * wv;
    }
    float a1 = a[lane], a2 = a[64 + lane];
#pragma unroll
    for (int r = 0; r < 4; ++r) {
      int nn = nn0 + r;
      Wh[(size_t)nn * 64 + lane] = acc[r];
      float p1 = acc[r] * a1, p2 = acc[r] * a2;
#pragma unroll
      for (int off = 32; off; off >>= 1) {
        p1 += __shfl_xor(p1, off, 64);
        p2 += __shfl_xor(p2, off, 64);
      }
      if (lane == 0) { s1[nn] = p1; s2[nn] = p2; }
    }
  }

  // ---- A2: bucket 1024 edges by src>>5 (LDS hist -> 256 global atomics) ----
  __syncthreads();
  int* bhist = (int*)smem;
  int* bbase = bhist + NB;
  int e = blk * 1024 + tid;
  int s = ei[e], d = ei[EDGES + e];
  int g = s >> 5;
  if (tid < NB) bhist[tid] = 0;
  __syncthreads();
  int rank = atomicAdd(&bhist[g], 1);
  __syncthreads();
  if (tid < NB) bbase[tid] = atomicAdd(&cnt[tid], bhist[tid]);
  __syncthreads();
  int pos = bbase[g] + rank;
  if (pos < BCAP)
    coarse[g * BCAP + pos] = make_uint2(((unsigned)e << 13) | (unsigned)d, (unsigned)s);
}

// K2: 512 blocks (B x NB) x 512 thr. Regroup bucket by src in LDS, then per wave:
// dedupe + masked softmax (1 edge/lane) and 4-lane-per-edge float4 gather.
__global__ __launch_bounds__(512, 4) void stage2_kernel(
    const float* __restrict__ ew, const float* __restrict__ s1,
    const float* __restrict__ s2, const int* __restrict__ cnt,
    const uint2* __restrict__ coarse, const float* __restrict__ Wh,
    float* __restrict__ out) {
  __shared__ uint2 grp[BCAP];
  __shared__ int rhist[SRCB];
  __shared__ int roffs[SRCB];
  int tid = threadIdx.x, lane = tid & 63, w = tid >> 6;   // 8 waves
  int blk = blockIdx.x;
  int xcd = blk & 7;
  int b = xcd >> 2;                            // XCD 0-3: batch 0, 4-7: batch 1
  int g = (blk >> 3) * 4 + (xcd & 3);          // [0, 256)
  int T = cnt[g]; if (T > BCAP) T = BCAP;
  const float* s1b = s1 + b * NN;
  const float* s2b = s2 + b * NN;
  if (tid < SRCB) rhist[tid] = 0;
  __syncthreads();

  unsigned mpk[3]; float mv[3]; int msl[3], mrk[3]; bool mok[3];
#pragma unroll
  for (int j = 0; j < 3; ++j) {
    int i = tid + j * 512;
    mok[j] = (i < T);
    mpk[j] = 0; mv[j] = 0.f; msl[j] = 0; mrk[j] = 0;
    if (mok[j]) {
      uint2 E = coarse[g * BCAP + i];
      int dst = (int)(E.x & 0x1FFFu);
      int eid = (int)(E.x >> 13);
      int src = (int)E.y;
      float x = s1b[src] + s2b[dst];
      float val = (x > 0.f ? x : ALPHA * x) * ew[eid];
      mpk[j] = E.x; mv[j] = val; msl[j] = src & (SRCB - 1);
      mrk[j] = atomicAdd(&rhist[msl[j]], 1);
    }
  }
  __syncthreads();
  if (tid < SRCB) {                            // exclusive scan of 32 counts (wave 0)
    int c = rhist[tid];
    int x = c;
#pragma unroll
    for (int off = 1; off < SRCB; off <<= 1) {
      int y = __shfl_up(x, off, 64);
      if (tid >= off) x += y;
    }
    roffs[tid] = x - c;
  }
  __syncthreads();
#pragma unroll
  for (int j = 0; j < 3; ++j)
    if (mok[j]) grp[roffs[msl[j]] + mrk[j]] = make_uint2(mpk[j], __float_as_uint(mv[j]));
  __syncthreads();

  const float* Whb = Wh + (size_t)b * NN * FDIM;
  int fg = lane & 15, es = lane >> 4;
  for (int q = 0; q < 4; ++q) {
    int slo = w * 4 + q;                       // src-in-bucket [0,32)
    int beg = roffs[slo];
    int deg = rhist[slo];
    int n = g * SRCB + slo;
    float4 r4 = make_float4(0.f, 0.f, 0.f, 0.f);
    if (deg > 0) {
      float inv;
      if (deg <= 64) {
        unsigned k0 = 0; float v0 = 0.f;
        if (lane < deg) { uint2 E = grp[beg + lane]; k0 = E.x; v0 = __uint_as_float(E.y); }
        for (int j = 0; j < deg; ++j) {
          unsigned q2 = __shfl(k0, j, 64);
          if ((((q2 ^ k0) & 0x1FFFu) == 0u) & (q2 > k0)) v0 = 0.f;   // dup loser
        }
        float m = (v0 != 0.f) ? v0 : -INFINITY;
#pragma unroll
        for (int off = 32; off; off >>= 1) m = fmaxf(m, __shfl_xor(m, off, 64));
        float p = (v0 != 0.f) ? expf(v0 - m) : 0.f;
        float sum = p;
#pragma unroll
        for (int off = 32; off; off >>= 1) sum += __shfl_xor(sum, off, 64);
        inv = (sum > 0.f) ? 1.f / sum : 0.f;
        if (lane < deg) grp[beg + lane].y = __float_as_uint(p);
      } else {                                 // deg in (64,128] — vanishingly rare
        int dg = deg > ROWCAP ? ROWCAP : deg;
        deg = dg;
        unsigned k0 = 0, k1 = 0; float v0 = 0.f, v1 = 0.f;
        { uint2 E = grp[beg + lane]; k0 = E.x; v0 = __uint_as_float(E.y); }
        if (lane + 64 < dg) { uint2 E = grp[beg + lane + 64]; k1 = E.x; v1 = __uint_as_float(E.y); }
        for (int j = 0; j < 64; ++j) {
          unsigned q2 = __shfl(k0, j, 64);
          if ((((q2 ^ k0) & 0x1FFFu) == 0u) & (q2 > k0)) v0 = 0.f;
          if ((((q2 ^ k1) & 0x1FFFu) == 0u) & (q2 > k1)) v1 = 0.f;
        }
        for (int j = 0; j < dg - 64; ++j) {
          unsigned q2 = __shfl(k1, j, 64);
          if ((((q2 ^ k0) & 0x1FFFu) == 0u) & (q2 > k0)) v0 = 0.f;
          if ((((q2 ^ k1) & 0x1FFFu) == 0u) & (q2 > k1)) v1 = 0.f;
        }
        float m = fmaxf((v0 != 0.f) ? v0 : -INFINITY, (v1 != 0.f) ? v1 : -INFINITY);
#pragma unroll
        for (int off = 32; off; off >>= 1) m = fmaxf(m, __shfl_xor(m, off, 64));
        float p0 = (v0 != 0.f) ? expf(v0 - m) : 0.f;
        float p1 = (v1 != 0.f) ? expf(v1 - m) : 0.f;
        float sum = p0 + p1;
#pragma unroll
        for (int off = 32; off; off >>= 1) sum += __shfl_xor(sum, off, 64);
        inv = (sum > 0.f) ? 1.f / sum : 0.f;
        grp[beg + lane].y = __float_as_uint(p0);
        if (lane + 64 < dg) grp[beg + lane + 64].y = __float_as_uint(p1);
      }
      // 4-lane-per-edge gather: lane (es,fg) does acc[fg*4..+3] += p_e * Wh[dst_e]
      float4 acc = make_float4(0.f, 0.f, 0.f, 0.f);
      for (int kk = 0; kk < deg; kk += 8) {
#pragma unroll
        for (int u = 0; u < 2; ++u) {
          int k = kk + u * 4 + es;
          int kc = k < deg ? k : deg - 1;      // clamp: stays a valid entry
          uint2 E = grp[beg + kc];
          float p = (k < deg) ? __uint_as_float(E.y) : 0.f;
          const float4* src4 = (const float4*)(Whb + (E.x & 0x1FFFu) * 64) + fg;
          float4 v = *src4;
          acc.x += p * v.x; acc.y += p * v.y; acc.z += p * v.z; acc.w += p * v.w;
        }
      }
#pragma unroll
      for (int off = 16; off <= 32; off <<= 1) {
        acc.x += __shfl_xor(acc.x, off, 64);
        acc.y += __shfl_xor(acc.y, off, 64);
        acc.z += __shfl_xor(acc.z, off, 64);
        acc.w += __shfl_xor(acc.w, off, 64);
      }
      r4.x = acc.x * inv; r4.y = acc.y * inv; r4.z = acc.z * inv; r4.w = acc.w * inv;
    }
    if (es == 0) {                             // lanes 0..15 store 64 floats
      r4.x = r4.x > 0.f ? r4.x : expm1f(r4.x);
      r4.y = r4.y > 0.f ? r4.y : expm1f(r4.y);
      r4.z = r4.z > 0.f ? r4.z : expm1f(r4.z);
      r4.w = r4.w > 0.f ? r4.w : expm1f(r4.w);
      *((float4*)(out + ((size_t)b * NN + n) * 64) + fg) = r4;
    }
  }
}

extern "C" void kernel_launch(void* const* d_in, const int* in_sizes, int n_in,
                              void* d_out, int out_size, void* d_ws, size_t ws_size,
                              hipStream_t stream) {
  const float* h  = (const float*)d_in[0];
  const float* W  = (const float*)d_in[1];
  const float* a  = (const float*)d_in[2];
  const int*   ei = (const int*)d_in[3];
  const float* ew = (const float*)d_in[4];
  float* out = (float*)d_out;

  char* ws = (char*)d_ws;
  float* Wh     = (float*)(ws + OFF_WH);
  float* s1     = (float*)(ws + OFF_S1);
  float* s2     = (float*)(ws + OFF_S2);
  int*   cnt    = (int*)(ws + OFF_CNT);
  uint2* coarse = (uint2*)(ws + OFF_CRS);

  hipMemsetAsync(cnt, 0, NB * sizeof(int), stream);
  stage1_kernel<<<256, 1024, 0, stream>>>(h, W, a, ei, Wh, s1, s2, cnt, coarse);
  stage2_kernel<<<BATCH * NB, 512, 0, stream>>>(ew, s1, s2, cnt, coarse, Wh, out);
}